// Round 1
// baseline (434.138 us; speedup 1.0000x reference)
//
#include <hip/hip_runtime.h>
#include <cstdint>
#include <cstddef>

#define N_B 64
#define C_C 192
#define V_V 25
#define T_T 300
#define D_D 192
#define TB 5
#define JP 125            // TB*V_V packed columns per block
#define NT2 60            // T_T / TB
#define GRID_B (N_B*NT2)  // 3840
#define LDS_BYTES 143200

typedef unsigned short u16;
typedef short bf16x8 __attribute__((ext_vector_type(8)));
typedef float f32x4 __attribute__((ext_vector_type(4)));

__device__ __forceinline__ u16 f2bf(float x) {
  union { float f; uint32_t u; } v; v.f = x;
  uint32_t r = v.u + 0x7fffu + ((v.u >> 16) & 1u);
  return (u16)(r >> 16);
}
__device__ __forceinline__ float bf2f(u16 b) {
  union { uint32_t u; float f; } v; v.u = ((uint32_t)b) << 16; return v.f;
}

// Convert W1, W2 (fp32 [D][C] row-major) to bf16 in workspace.
__global__ __launch_bounds__(256) void prep_w(const float* __restrict__ w1,
                                              const float* __restrict__ w2,
                                              u16* __restrict__ wb) {
  int i = blockIdx.x * 256 + threadIdx.x;
  if (i < C_C * D_D) {
    wb[i] = f2bf(w1[i]);
    wb[C_C * D_D + i] = f2bf(w2[i]);
  }
}

// One block handles one n and TB=5 consecutive t values.
// LDS map (bytes):
//   [0,      64000)  GT1 [160][200] bf16  (rows tt*32+vv, col d; col-25 row = mean)
//   [64000, 128000)  GT2 [160][200] bf16
//   [0,      51200)  XT  [128][200] bf16  (overlaps GT1; dead after pass1)
//   [128000,142560)  SIM [5][26][28] fp32
//   [142560,143200)  MASKL [5][32] fp32
__global__ __launch_bounds__(512, 2) void fused(const float* __restrict__ x1,
                                                const u16* __restrict__ wb,
                                                const float* __restrict__ wm,
                                                float* __restrict__ out) {
  extern __shared__ char lds[];
  u16* GT1 = (u16*)lds;
  u16* GT2 = (u16*)(lds + 64000);
  u16* XT  = (u16*)lds;
  float* SIM = (float*)(lds + 128000);
  float* MASKL = (float*)(lds + 142560);

  const int tid = threadIdx.x;
  const int wid = tid >> 6;
  const int lane = tid & 63;
  const int lr = lane & 15;   // row/col-in-tile
  const int lq = lane >> 4;   // quarter index 0..3

  // XCD-chunked bijective swizzle: consecutive logical blocks (same n, adjacent t)
  // land on the same XCD so x1 cachelines (64B = 16 t's) are L2-shared.
  int b = blockIdx.x;
  int logical = (b & 7) * (GRID_B / 8) + (b >> 3);
  int n = logical / NT2;
  int tb = logical - n * NT2;
  int t0 = tb * TB;

  // ---- stage X -> XT bf16, row j = v*TB + tt, col c ----
  const float* xb = x1 + (size_t)n * (C_C * V_V * T_T) + t0;
  for (int idx = tid; idx < C_C * JP; idx += 512) {
    int c = idx / JP;
    int j = idx - c * JP;
    int v = j / TB;
    int tt = j - v * TB;
    XT[j * 200 + c] = f2bf(xb[(c * V_V + v) * T_T + tt]);
  }
  __syncthreads();

  // ---- pass1: G1 = W1 @ X, G2 = W2 @ X  (M=192, N=128, K=192) ----
  const int mg = wid >> 1;  // 4 M-groups x 48 rows
  const int ng = wid & 1;   // 2 N-groups x 64 cols
  f32x4 acc[2][3][4];
  #pragma unroll
  for (int m = 0; m < 2; m++)
    #pragma unroll
    for (int a = 0; a < 3; a++)
      #pragma unroll
      for (int q = 0; q < 4; q++) acc[m][a][q] = (f32x4){0.f, 0.f, 0.f, 0.f};

  #pragma unroll
  for (int ks = 0; ks < 6; ++ks) {
    bf16x8 bfr[4];
    #pragma unroll
    for (int nt = 0; nt < 4; ++nt) {
      int j = ng * 64 + nt * 16 + lr;
      bfr[nt] = *(const bf16x8*)(XT + j * 200 + ks * 32 + lq * 8);
    }
    #pragma unroll
    for (int mt = 0; mt < 3; ++mt) {
      int d = mg * 48 + mt * 16 + lr;
      const u16* wp = wb + d * C_C + ks * 32 + lq * 8;
      bf16x8 a1 = *(const bf16x8*)wp;
      bf16x8 a2 = *(const bf16x8*)(wp + C_C * D_D);
      #pragma unroll
      for (int nt = 0; nt < 4; ++nt) {
        acc[0][mt][nt] = __builtin_amdgcn_mfma_f32_16x16x32_bf16(a1, bfr[nt], acc[0][mt][nt], 0, 0, 0);
        acc[1][mt][nt] = __builtin_amdgcn_mfma_f32_16x16x32_bf16(a2, bfr[nt], acc[1][mt][nt], 0, 0, 0);
      }
    }
  }

  // ---- mask[t][v] = sum_c X[c,v] * wm[c]  (read XT before it is overwritten) ----
  if (tid < JP) {
    int v = tid / TB, tt = tid - v * TB;
    float s = 0.f;
    #pragma unroll 8
    for (int c = 0; c < C_C; ++c) s += bf2f(XT[tid * 200 + c]) * wm[c];
    MASKL[tt * 32 + v] = s;
  }
  __syncthreads();  // all XT reads done before GT overwrite

  // ---- write G transposed: GT[tt*32+vv][d] bf16 ----
  #pragma unroll
  for (int m = 0; m < 2; ++m) {
    u16* G = m ? GT2 : GT1;
    #pragma unroll
    for (int mt = 0; mt < 3; ++mt) {
      #pragma unroll
      for (int nt = 0; nt < 4; ++nt) {
        int jc = ng * 64 + nt * 16 + lr;
        if (jc < JP) {
          int v = jc / TB, tt = jc - v * TB;
          u16* g = G + (tt * 32 + v) * 200 + mg * 48 + mt * 16 + lq * 4;
          f32x4 a = acc[m][mt][nt];
          g[0] = f2bf(a[0]); g[1] = f2bf(a[1]); g[2] = f2bf(a[2]); g[3] = f2bf(a[3]);
        }
      }
    }
  }
  __syncthreads();

  // ---- means over v -> column 25 of each t-group ----
  for (int job = tid; job < 2 * TB * D_D; job += 512) {
    int m = job / (TB * D_D);
    int r = job - m * (TB * D_D);
    int tt = r / D_D;
    int d = r - tt * D_D;
    u16* g = (m ? GT2 : GT1) + (tt * 32) * 200 + d;
    float s = 0.f;
    #pragma unroll
    for (int v = 0; v < V_V; ++v) s += bf2f(g[v * 200]);
    g[25 * 200] = f2bf(s * 0.04f);  // 1/25
  }
  __syncthreads();

  // ---- pass2: sim'[vv][ww] = sum_d G1t[vv][d]*G2t[ww][d]  per t (M=N=32, K=192) ----
  for (int job = wid; job < 4 * TB; job += 8) {
    int t5 = job >> 2;
    int vt = (job >> 1) & 1, wt = job & 1;
    f32x4 s = (f32x4){0.f, 0.f, 0.f, 0.f};
    const u16* ga = GT1 + (t5 * 32 + vt * 16 + lr) * 200;
    const u16* gb = GT2 + (t5 * 32 + wt * 16 + lr) * 200;
    #pragma unroll
    for (int ks = 0; ks < 6; ++ks) {
      bf16x8 a = *(const bf16x8*)(ga + ks * 32 + lq * 8);
      bf16x8 bb = *(const bf16x8*)(gb + ks * 32 + lq * 8);
      s = __builtin_amdgcn_mfma_f32_16x16x32_bf16(a, bb, s, 0, 0, 0);
    }
    int w = wt * 16 + lr;
    if (w < 26) {
      #pragma unroll
      for (int i = 0; i < 4; ++i) {
        int v = vt * 16 + lq * 4 + i;
        if (v < 26) SIM[(t5 * 26 + v) * 28 + w] = s[i];
      }
    }
  }
  __syncthreads();

  // ---- centering correction + mask + softmax + store ----
  const float isc = 0.07216878365f;  // 1/sqrt(192)
  for (int row = tid; row < TB * V_V; row += 512) {
    int t5 = row / V_V, v = row - t5 * V_V;
    const float* sb = SIM + (t5 * 26) * 28;
    float c00 = sb[25 * 28 + 25];
    float av = sb[v * 28 + 25];
    float l[V_V];
    float mx = -1e30f;
    #pragma unroll
    for (int w = 0; w < V_V; ++w) {
      float val = (sb[v * 28 + w] - av - sb[25 * 28 + w] + c00) * isc + MASKL[t5 * 32 + w];
      l[w] = val;
      mx = fmaxf(mx, val);
    }
    float sum = 0.f;
    #pragma unroll
    for (int w = 0; w < V_V; ++w) { float e = __expf(l[w] - mx); l[w] = e; sum += e; }
    float rs = 1.0f / sum;
    float* o = out + (((size_t)n * T_T + t0 + t5) * V_V + v) * V_V;
    #pragma unroll
    for (int w = 0; w < V_V; ++w) o[w] = l[w] * rs;
  }
}

extern "C" void kernel_launch(void* const* d_in, const int* in_sizes, int n_in,
                              void* d_out, int out_size, void* d_ws, size_t ws_size,
                              hipStream_t stream) {
  const float* x1 = (const float*)d_in[0];
  const float* w1 = (const float*)d_in[1];
  const float* w2 = (const float*)d_in[2];
  const float* wm = (const float*)d_in[3];
  float* out = (float*)d_out;
  u16* wb = (u16*)d_ws;  // 2 * 192*192 bf16 = 147,456 B

  hipLaunchKernelGGL(prep_w, dim3((C_C * D_D + 255) / 256), dim3(256), 0, stream, w1, w2, wb);
  hipLaunchKernelGGL(fused, dim3(GRID_B), dim3(512), LDS_BYTES, stream, x1, wb, wm, out);
}

// Round 2
// 423.496 us; speedup vs baseline: 1.0251x; 1.0251x over previous
//
#include <hip/hip_runtime.h>
#include <cstdint>
#include <cstddef>

#define NN 64
#define CC 192
#define VV 25
#define TTT 300
#define TB 4
#define NTB 75          // 300/4
#define GRID (NN*NTB)   // 4800
#define ROWB 384        // LDS row bytes = 192 * 2
#define XT_OFF 0
#define YT_OFF 49152
#define SIM_OFF 98304
#define MSK_OFF 109952
#define LDS_BYTES 110400

typedef unsigned short u16;
typedef short bf16x8 __attribute__((ext_vector_type(8)));
typedef float f32x4 __attribute__((ext_vector_type(4)));
typedef float f4 __attribute__((ext_vector_type(4)));

__device__ __forceinline__ u16 f2bf(float x) {
  union { float f; uint32_t u; } v; v.f = x;
  uint32_t r = v.u + 0x7fffu + ((v.u >> 16) & 1u);
  return (u16)(r >> 16);
}
__device__ __forceinline__ float bf2f(u16 b) {
  union { uint32_t u; float f; } v; v.u = ((uint32_t)b) << 16; return v.f;
}
// XOR swizzle: rows are 384 B (bank-aligned); spread 16B units across 8 slots by row.
__device__ __forceinline__ int swz(int row, int colb) {
  return row * ROWB + (colb ^ ((row & 7) << 4));
}

// M[c1][c2] = sum_d w1[d][c1] * w2[d][c2], bf16 out. 192 blocks x 192 threads.
__global__ __launch_bounds__(192) void prep_m(const float* __restrict__ w1,
                                              const float* __restrict__ w2,
                                              u16* __restrict__ mb) {
  int c1 = blockIdx.x, c2 = threadIdx.x;
  float s = 0.f;
  for (int d = 0; d < CC; ++d) s += w1[d * CC + c1] * w2[d * CC + c2];
  mb[c1 * CC + c2] = f2bf(s);
}

// One block: one n, TB=4 consecutive t.  LDS:
//  XT [128 rows = tt*32+v][192 c] bf16 swizzled (row 25 of each tt = mean over v)
//  YT [128 rows = tt*32+w][192 c1] bf16 swizzled (Y = M @ X, transposed)
//  SIM [4][26][28] f32, MSK [4][28] f32
__global__ __launch_bounds__(512, 2) void fused(const float* __restrict__ x1,
                                                const u16* __restrict__ mb,
                                                const float* __restrict__ wm,
                                                float* __restrict__ out) {
  extern __shared__ char lds[];
  char* XT = lds + XT_OFF;
  char* YT = lds + YT_OFF;
  float* SIM = (float*)(lds + SIM_OFF);
  float* MSK = (float*)(lds + MSK_OFF);

  const int tid = threadIdx.x;
  const int wid = tid >> 6;
  const int lane = tid & 63;
  const int lr = lane & 15;
  const int lq = lane >> 4;

  // XCD-chunked bijective swizzle (GRID % 8 == 0): same-n adjacent-t blocks share L2.
  int b = blockIdx.x;
  int logical = (b & 7) * (GRID / 8) + (b >> 3);
  int n = logical / NTB;
  int tb = logical - n * NTB;
  int t0 = tb * TB;

  // ---- stage: float4 over t (16B-aligned since t0 % 4 == 0), b64 LDS writes ----
  const float* xb = x1 + (size_t)n * (CC * VV * TTT) + t0;
  for (int job = tid; job < 1200; job += 512) {
    int cq = job / 25, v = job - cq * 25;          // c-quad, v
    const float* p = xb + (cq * 4 * VV + v) * TTT;
    f4 a0 = *(const f4*)(p);
    f4 a1 = *(const f4*)(p + VV * TTT);
    f4 a2 = *(const f4*)(p + 2 * VV * TTT);
    f4 a3 = *(const f4*)(p + 3 * VV * TTT);
    #pragma unroll
    for (int tt = 0; tt < 4; ++tt) {
      uint64_t pk = (uint64_t)f2bf(a0[tt]) | ((uint64_t)f2bf(a1[tt]) << 16) |
                    ((uint64_t)f2bf(a2[tt]) << 32) | ((uint64_t)f2bf(a3[tt]) << 48);
      *(uint64_t*)(XT + swz(tt * 32 + v, cq * 8)) = pk;
    }
  }
  __syncthreads();

  // ---- mean rows (row 25 per tt) + mask (parallel, disjoint) ----
  for (int job = tid; job < TB * CC; job += 512) {
    int tt = job / CC, c = job - tt * CC;
    float s = 0.f;
    #pragma unroll
    for (int v = 0; v < VV; ++v) s += bf2f(*(const u16*)(XT + swz(tt * 32 + v, c * 2)));
    *(u16*)(XT + swz(tt * 32 + 25, c * 2)) = f2bf(s * 0.04f);
  }
  if (tid < 400) {
    int g = tid >> 2, sub = tid & 3;
    int tt = g / 25, v = g - tt * 25;
    float s = 0.f;
    #pragma unroll 8
    for (int c = sub * 48; c < sub * 48 + 48; ++c)
      s += bf2f(*(const u16*)(XT + swz(tt * 32 + v, c * 2))) * wm[c];
    s += __shfl_xor(s, 1);
    s += __shfl_xor(s, 2);
    if (sub == 0) MSK[tt * 28 + v] = s;
  }
  __syncthreads();

  // ---- pass1: Y = M @ X   (M=192 x N=128 x K=192), 8 waves = 2 mg x 4 ng ----
  const int mg = wid >> 2;   // 2 groups x 6 M-tiles (96 rows)
  const int ng = wid & 3;    // 4 groups x 2 N-tiles (32 cols)
  f32x4 acc[6][2];
  #pragma unroll
  for (int mt = 0; mt < 6; ++mt)
    #pragma unroll
    for (int nt = 0; nt < 2; ++nt) acc[mt][nt] = (f32x4){0.f, 0.f, 0.f, 0.f};

  #pragma unroll
  for (int ks = 0; ks < 6; ++ks) {
    bf16x8 bf[2];
    #pragma unroll
    for (int nt = 0; nt < 2; ++nt) {
      int j = (ng * 2 + nt) * 16 + lr;
      bf[nt] = *(const bf16x8*)(XT + swz(j, (ks * 32 + lq * 8) * 2));
    }
    #pragma unroll
    for (int mt = 0; mt < 6; ++mt) {
      int c1 = mg * 96 + mt * 16 + lr;
      bf16x8 a = *(const bf16x8*)(mb + c1 * CC + ks * 32 + lq * 8);
      acc[mt][0] = __builtin_amdgcn_mfma_f32_16x16x32_bf16(a, bf[0], acc[mt][0], 0, 0, 0);
      acc[mt][1] = __builtin_amdgcn_mfma_f32_16x16x32_bf16(a, bf[1], acc[mt][1], 0, 0, 0);
    }
  }

  // ---- write Y transposed: YT[j=col][c1=row] via packed b64 (4 consecutive c1/lane) ----
  #pragma unroll
  for (int mt = 0; mt < 6; ++mt) {
    #pragma unroll
    for (int nt = 0; nt < 2; ++nt) {
      int j = (ng * 2 + nt) * 16 + lr;
      int c1b = (mg * 96 + mt * 16 + lq * 4) * 2;
      f32x4 a = acc[mt][nt];
      uint64_t pk = (uint64_t)f2bf(a[0]) | ((uint64_t)f2bf(a[1]) << 16) |
                    ((uint64_t)f2bf(a[2]) << 32) | ((uint64_t)f2bf(a[3]) << 48);
      *(uint64_t*)(YT + swz(j, c1b)) = pk;
    }
  }
  __syncthreads();

  // ---- pass2: sim'[v][w] = sum_c1 X[c1,v]*Y[c1,w]; 16 jobs (tt,vt,wt) / 8 waves ----
  for (int job = wid; job < 16; job += 8) {
    int tt = job >> 2, vt = (job >> 1) & 1, wt = job & 1;
    f32x4 s = (f32x4){0.f, 0.f, 0.f, 0.f};
    int ar = tt * 32 + vt * 16 + lr;
    int br = tt * 32 + wt * 16 + lr;
    #pragma unroll
    for (int ks = 0; ks < 6; ++ks) {
      bf16x8 a = *(const bf16x8*)(XT + swz(ar, (ks * 32 + lq * 8) * 2));
      bf16x8 bb = *(const bf16x8*)(YT + swz(br, (ks * 32 + lq * 8) * 2));
      s = __builtin_amdgcn_mfma_f32_16x16x32_bf16(a, bb, s, 0, 0, 0);
    }
    int w = wt * 16 + lr;
    if (w < 26) {
      #pragma unroll
      for (int i = 0; i < 4; ++i) {
        int v = vt * 16 + lq * 4 + i;
        if (v < 26) SIM[(tt * 26 + v) * 28 + w] = s[i];
      }
    }
  }
  __syncthreads();

  // ---- centering correction + mask + softmax (probs written back to SIM) ----
  if (tid < 100) {
    int tt = tid / 25, v = tid - tt * 25;
    float* sb = SIM + tt * 26 * 28;
    const float c00 = sb[25 * 28 + 25];
    const float rm = sb[v * 28 + 25];
    const float isc = 0.07216878364870323f;  // 1/sqrt(192)
    float l[VV];
    float mx = -1e30f;
    #pragma unroll
    for (int w = 0; w < VV; ++w) {
      float val = (sb[v * 28 + w] - sb[25 * 28 + w] - rm + c00) * isc + MSK[tt * 28 + w];
      l[w] = val;
      mx = fmaxf(mx, val);
    }
    float sum = 0.f;
    #pragma unroll
    for (int w = 0; w < VV; ++w) { float e = __expf(l[w] - mx); l[w] = e; sum += e; }
    float rs = 1.0f / sum;
    #pragma unroll
    for (int w = 0; w < VV; ++w) sb[v * 28 + w] = l[w] * rs;
  }
  __syncthreads();

  // ---- coalesced store: out slab for (n, t0..t0+3) is 4*625 contiguous floats ----
  float* ob = out + ((size_t)n * TTT + t0) * 625;
  for (int idx = tid; idx < TB * 625; idx += 512) {
    int tt = idx / 625;
    int r = idx - tt * 625;
    int v = r / 25;
    int w = r - v * 25;
    ob[idx] = SIM[(tt * 26 + v) * 28 + w];
  }
}

extern "C" void kernel_launch(void* const* d_in, const int* in_sizes, int n_in,
                              void* d_out, int out_size, void* d_ws, size_t ws_size,
                              hipStream_t stream) {
  const float* x1 = (const float*)d_in[0];
  const float* w1 = (const float*)d_in[1];
  const float* w2 = (const float*)d_in[2];
  const float* wm = (const float*)d_in[3];
  float* out = (float*)d_out;
  u16* mb = (u16*)d_ws;  // 192*192 bf16 = 73,728 B

  hipLaunchKernelGGL(prep_m, dim3(CC), dim3(CC), 0, stream, w1, w2, mb);
  hipLaunchKernelGGL(fused, dim3(GRID), dim3(512), LDS_BYTES, stream, x1, mb, wm, out);
}

// Round 3
// 338.941 us; speedup vs baseline: 1.2809x; 1.2495x over previous
//
#include <hip/hip_runtime.h>
#include <cstdint>
#include <cstddef>

#define NN 64
#define CC 192
#define VV 25
#define TTT 300
#define TB 3
#define NTB 100         // 300/3
#define GRID (NN*NTB)   // 6400
#define ROWB 384        // LDS row bytes = 192 * 2
// LDS byte offsets
#define XT_OFF 0        // 82 rows x 384B (rows tt*25+v; reads may spill into YT: garbage-safe)
#define YT_OFF 31488    // 96 rows x 384B
#define SIM_OFF 68352   // [3][25][28] f32
#define MSK_OFF 76752   // [3][28] f32
#define RS_OFF 77088    // [3][28] f32 row sums
#define CS_OFF 77424    // [3][28] f32 col sums
#define LDS_BYTES 77760 // <= 81920 -> 2 blocks/CU
#define WMEXT_OFF 36864 // u16 elements into ws: 16x192 block, row0 = wm

typedef unsigned short u16;
typedef short bf16x8 __attribute__((ext_vector_type(8)));
typedef float f32x4 __attribute__((ext_vector_type(4)));

__device__ __forceinline__ u16 f2bf(float x) {
  union { float f; uint32_t u; } v; v.f = x;
  uint32_t r = v.u + 0x7fffu + ((v.u >> 16) & 1u);
  return (u16)(r >> 16);
}
// XOR swizzle on 384B rows: spread 16B units across 8 slots by row (kills stride-384 conflicts).
__device__ __forceinline__ int swz(int row, int colb) {
  return row * ROWB + (colb ^ ((row & 7) << 4));
}

// blocks 0..191: M[c1][c2] = sum_d w1[d][c1]*w2[d][c2] (bf16).
// block 192: wmext 16x192 (row0 = wm bf16, rows 1..15 = 0) for the mask-MFMA.
__global__ __launch_bounds__(192) void prep(const float* __restrict__ w1,
                                            const float* __restrict__ w2,
                                            const float* __restrict__ wm,
                                            u16* __restrict__ mb) {
  int c2 = threadIdx.x;
  int b = blockIdx.x;
  if (b < CC) {
    float s = 0.f;
    for (int d = 0; d < CC; ++d) s += w1[d * CC + b] * w2[d * CC + c2];
    mb[b * CC + c2] = f2bf(s);
  } else {
    mb[WMEXT_OFF + c2] = f2bf(wm[c2]);
    #pragma unroll
    for (int r = 1; r < 16; ++r) mb[WMEXT_OFF + r * CC + c2] = 0;
  }
}

// One block: one n, TB=3 consecutive t. Phases:
// stage X -> XT | pass1 Y = M@X -> YT | pass2 sim'=X^T Y + mask-MFMA | stats | softmax+store
__global__ __launch_bounds__(512, 4) void fused(const float* __restrict__ x1,
                                                const u16* __restrict__ mb,
                                                float* __restrict__ out) {
  extern __shared__ char lds[];
  char* XT = lds + XT_OFF;
  char* YT = lds + YT_OFF;
  float* SIM = (float*)(lds + SIM_OFF);
  float* MSK = (float*)(lds + MSK_OFF);
  float* RS = (float*)(lds + RS_OFF);
  float* CS = (float*)(lds + CS_OFF);

  const int tid = threadIdx.x;
  const int wid = tid >> 6;
  const int lane = tid & 63;
  const int lr = lane & 15;
  const int lq = lane >> 4;

  // XCD-chunked bijective swizzle (GRID % 8 == 0).
  int b = blockIdx.x;
  int logical = (b & 7) * (GRID / 8) + (b >> 3);
  int n = logical / NTB;
  int tb = logical - n * NTB;
  int t0 = tb * TB;

  // ---- stage: per (c-quad, v): 12 dword loads (t0 not 16B-aligned), 3 packed b64 LDS writes ----
  const float* xb = x1 + (size_t)n * (CC * VV * TTT) + t0;
  for (int job = tid; job < 1200; job += 512) {
    int cq = job / 25, v = job - cq * 25;
    const float* p = xb + (cq * 4 * VV + v) * TTT;
    float a[4][TB];
    #pragma unroll
    for (int i = 0; i < 4; ++i) {
      const float* q = p + i * VV * TTT;
      a[i][0] = q[0]; a[i][1] = q[1]; a[i][2] = q[2];
    }
    #pragma unroll
    for (int tt = 0; tt < TB; ++tt) {
      uint64_t pk = (uint64_t)f2bf(a[0][tt]) | ((uint64_t)f2bf(a[1][tt]) << 16) |
                    ((uint64_t)f2bf(a[2][tt]) << 32) | ((uint64_t)f2bf(a[3][tt]) << 48);
      *(uint64_t*)(XT + swz(tt * 25 + v, cq * 8)) = pk;
    }
  }
  __syncthreads();

  // ---- pass1: Y = M @ X  (M=192 x N=96 x K=192); 8 waves = 4 mg x 2 ng, acc[3][3] ----
  const int mg = wid >> 1;  // 4 groups x 3 M-tiles (48 rows)
  const int ng = wid & 1;   // 2 groups x 3 N-tiles (48 cols)
  f32x4 acc[3][3];
  #pragma unroll
  for (int mt = 0; mt < 3; ++mt)
    #pragma unroll
    for (int nt = 0; nt < 3; ++nt) acc[mt][nt] = (f32x4){0.f, 0.f, 0.f, 0.f};

  #pragma unroll
  for (int ks = 0; ks < 6; ++ks) {
    bf16x8 bfr[3];
    #pragma unroll
    for (int nt = 0; nt < 3; ++nt) {
      int j = ng * 48 + nt * 16 + lr;
      bfr[nt] = *(const bf16x8*)(XT + swz(j, ks * 64 + lq * 16));
    }
    #pragma unroll
    for (int mt = 0; mt < 3; ++mt) {
      int c1 = mg * 48 + mt * 16 + lr;
      bf16x8 a = *(const bf16x8*)(mb + c1 * CC + ks * 32 + lq * 8);
      #pragma unroll
      for (int nt = 0; nt < 3; ++nt)
        acc[mt][nt] = __builtin_amdgcn_mfma_f32_16x16x32_bf16(a, bfr[nt], acc[mt][nt], 0, 0, 0);
    }
  }
  // write Y transposed: YT[j][c1], 4 consecutive c1 per lane packed to b64
  #pragma unroll
  for (int mt = 0; mt < 3; ++mt) {
    #pragma unroll
    for (int nt = 0; nt < 3; ++nt) {
      int j = ng * 48 + nt * 16 + lr;
      int c1b = (mg * 48 + mt * 16 + lq * 4) * 2;
      f32x4 a = acc[mt][nt];
      uint64_t pk = (uint64_t)f2bf(a[0]) | ((uint64_t)f2bf(a[1]) << 16) |
                    ((uint64_t)f2bf(a[2]) << 32) | ((uint64_t)f2bf(a[3]) << 48);
      *(uint64_t*)(YT + swz(j, c1b)) = pk;
    }
  }
  __syncthreads();

  // ---- pass2: 12 sim jobs (tt,vt,wt) + 6 mask jobs (tt,wt) ----
  for (int job = wid; job < 18; job += 8) {
    if (job < 12) {
      int tt = job >> 2, vt = (job >> 1) & 1, wt = job & 1;
      int ar = tt * 25 + vt * 16 + lr;
      int br = tt * 25 + wt * 16 + lr;
      f32x4 s = (f32x4){0.f, 0.f, 0.f, 0.f};
      #pragma unroll
      for (int ks = 0; ks < 6; ++ks) {
        bf16x8 a = *(const bf16x8*)(XT + swz(ar, ks * 64 + lq * 16));
        bf16x8 bb = *(const bf16x8*)(YT + swz(br, ks * 64 + lq * 16));
        s = __builtin_amdgcn_mfma_f32_16x16x32_bf16(a, bb, s, 0, 0, 0);
      }
      int w = wt * 16 + lr;
      if (w < VV) {
        #pragma unroll
        for (int i = 0; i < 4; ++i) {
          int v = vt * 16 + lq * 4 + i;
          if (v < VV) SIM[(tt * VV + v) * 28 + w] = s[i];
        }
      }
    } else {
      int m = job - 12;
      int tt = m >> 1, wt = m & 1;
      int br = tt * 25 + wt * 16 + lr;
      f32x4 s = (f32x4){0.f, 0.f, 0.f, 0.f};
      #pragma unroll
      for (int ks = 0; ks < 6; ++ks) {
        bf16x8 a = *(const bf16x8*)(mb + WMEXT_OFF + lr * CC + ks * 32 + lq * 8);
        bf16x8 bb = *(const bf16x8*)(XT + swz(br, ks * 64 + lq * 16));
        s = __builtin_amdgcn_mfma_f32_16x16x32_bf16(a, bb, s, 0, 0, 0);
      }
      int w = wt * 16 + lr;
      if (lq == 0 && w < VV) MSK[tt * 28 + w] = s[0];  // row 0 = wm
    }
  }
  __syncthreads();

  // ---- stats: row sums and col sums of each 25x25 sim ----
  if (tid < 150) {
    int q = tid / 25, idx = tid - q * 25;
    int tt = q >> 1;
    const float* sb = SIM + tt * VV * 28;
    float s = 0.f;
    if (q & 1) {  // row sum, v = idx
      #pragma unroll
      for (int w = 0; w < VV; ++w) s += sb[idx * 28 + w];
      RS[tt * 28 + idx] = s;
    } else {      // col sum, w = idx
      #pragma unroll
      for (int v = 0; v < VV; ++v) s += sb[v * 28 + idx];
      CS[tt * 28 + idx] = s;
    }
  }
  __syncthreads();

  // ---- centering (S - rowsum/25 - colsum/25 + tot/625) + mask + softmax + direct store ----
  if (tid < TB * VV) {
    int tt = tid / VV, v = tid - tt * VV;
    const float* sb = SIM + (tt * VV + v) * 28;
    const float* cs = CS + tt * 28;
    float tot = 0.f;
    #pragma unroll
    for (int w = 0; w < VV; ++w) tot += cs[w];
    const float base = -RS[tt * 28 + v] * 0.04f + tot * 0.0016f;
    const float isc = 0.07216878364870323f;  // 1/sqrt(192)
    float l[VV];
    float mx = -1e30f;
    #pragma unroll
    for (int w = 0; w < VV; ++w) {
      float val = (sb[w] - cs[w] * 0.04f + base) * isc + MSK[tt * 28 + w];
      l[w] = val;
      mx = fmaxf(mx, val);
    }
    float sum = 0.f;
    #pragma unroll
    for (int w = 0; w < VV; ++w) { float e = __expf(l[w] - mx); l[w] = e; sum += e; }
    float rs = 1.0f / sum;
    float* o = out + (((size_t)n * TTT + t0 + tt) * VV + v) * VV;
    #pragma unroll
    for (int w = 0; w < VV; ++w) o[w] = l[w] * rs;
  }
}

extern "C" void kernel_launch(void* const* d_in, const int* in_sizes, int n_in,
                              void* d_out, int out_size, void* d_ws, size_t ws_size,
                              hipStream_t stream) {
  const float* x1 = (const float*)d_in[0];
  const float* w1 = (const float*)d_in[1];
  const float* w2 = (const float*)d_in[2];
  const float* wm = (const float*)d_in[3];
  float* out = (float*)d_out;
  u16* mb = (u16*)d_ws;  // (192*192 + 16*192) bf16 = 79,872 B

  hipLaunchKernelGGL(prep, dim3(CC + 1), dim3(CC), 0, stream, w1, w2, wm, mb);
  hipLaunchKernelGGL(fused, dim3(GRID), dim3(512), LDS_BYTES, stream, x1, mb, out);
}